// Round 3
// baseline (173.095 us; speedup 1.0000x reference)
//
#include <hip/hip_runtime.h>
#include <hip/hip_bf16.h>
#include <stdint.h>

#define NB 8192
#define ND 1024
#define SCALE 20.0f   // 1/TEMPERATURE

typedef __bf16 bf16x8 __attribute__((ext_vector_type(8)));
typedef float  f32x4  __attribute__((ext_vector_type(4)));

// ---------------- input-format detection (device-side, deterministic) -------
__device__ inline void detect_formats(const void* rel_raw, const void* ist_raw,
                                      int& rel64, int& bmode) {
  const unsigned int* r = (const unsigned int*)rel_raw;
  int is64 = 1;
  for (int i = 1; i < 256; i += 2) {
    if (r[i] != 0u) { is64 = 0; break; }
  }
  rel64 = is64;
  const unsigned int* t = (const unsigned int*)ist_raw;
  bool sawf = false, sawbig = false;
  for (int i = 0; i < 64; ++i) {
    unsigned int w = t[i];
    if (w == 0x3F800000u) sawf = true;
    else if (w > 1u) sawbig = true;
  }
  bmode = sawf ? 2 : (sawbig ? 1 : 0);
}

__device__ inline int decode_key(const void* rel_raw, const void* ist_raw,
                                 int rel64, int bmode, int i) {
  const int* r32 = (const int*)rel_raw;
  int r = rel64 ? r32[2 * i] : r32[i];
  int truth;
  if (bmode == 1)      truth = (((const unsigned char*)ist_raw)[i] != 0);
  else if (bmode == 2) truth = (((const float*)ist_raw)[i] != 0.0f);
  else                 truth = (((const int*)ist_raw)[i] != 0);
  return truth ? r : -1;
}

__device__ inline bf16x8 cvt8(const float4& a, const float4& b) {
  bf16x8 v;
  v[0] = (__bf16)a.x; v[1] = (__bf16)a.y; v[2] = (__bf16)a.z; v[3] = (__bf16)a.w;
  v[4] = (__bf16)b.x; v[5] = (__bf16)b.y; v[6] = (__bf16)b.z; v[7] = (__bf16)b.w;
  return v;
}

// ---------------- prep: f32->bf16 convert + zero accumulators + decode keys -
__global__ void prep_kernel(const float* __restrict__ emb,
                            const void* __restrict__ rel_raw,
                            const void* __restrict__ ist_raw,
                            __bf16* __restrict__ embB,
                            float* __restrict__ sum_exp,
                            float* __restrict__ numer,
                            int* __restrict__ key) {
  int tid = blockIdx.x * 256 + threadIdx.x;
  size_t base = (size_t)tid * 8;
  if (base < (size_t)NB * ND) {
    float4 a = *(const float4*)(emb + base);
    float4 b = *(const float4*)(emb + base + 4);
    *(bf16x8*)(embB + base) = cvt8(a, b);
  }
  if (tid < NB) { sum_exp[tid] = 0.f; numer[tid] = 0.f; }
  __shared__ int s_rel64, s_bmode;
  if (blockIdx.x < 32) {                 // block-uniform branch
    if (threadIdx.x == 0) {
      int a, b; detect_formats(rel_raw, ist_raw, a, b);
      s_rel64 = a; s_bmode = b;
    }
    __syncthreads();
    int i = blockIdx.x * 256 + threadIdx.x;   // < 8192
    key[i] = decode_key(rel_raw, ist_raw, s_rel64, s_bmode, i);
  }
}

// small-ws fallback prep (no bf16 buffer)
__global__ void prep_small_kernel(const void* __restrict__ rel_raw,
                                  const void* __restrict__ ist_raw,
                                  float* __restrict__ sum_exp,
                                  float* __restrict__ numer,
                                  int* __restrict__ key) {
  int i = blockIdx.x * 256 + threadIdx.x;     // 32 blocks -> 8192
  sum_exp[i] = 0.f; numer[i] = 0.f;
  __shared__ int s_rel64, s_bmode;
  if (threadIdx.x == 0) {
    int a, b; detect_formats(rel_raw, ist_raw, a, b);
    s_rel64 = a; s_bmode = b;
  }
  __syncthreads();
  key[i] = decode_key(rel_raw, ist_raw, s_rel64, s_bmode, i);
}

// ============================================================================
// 8-phase 256x256 fused symmetric GEMM (T2 swizzle + T3/T4 counted vmcnt + T5)
// ============================================================================
// LDS tile layout (per 256x64 bf16 operand tile): subtiled [band=row/16]
// [cband=col/32][r4=row%16][c32=col%32], each subtile 1024B, with 16B-block
// swizzle: block index (c32/8) XOR'd with (r4>>1)&3.  ds_read_b128 is then
// ~2-way bank aliased (free).  global_load_lds stages one subtile per
// instruction (64 lanes x 16B); the source address carries the inverse
// permutation (same involution).

#define PH_SYNC() do { __builtin_amdgcn_s_barrier(); \
    asm volatile("s_waitcnt lgkmcnt(0)" ::: "memory"); \
    __builtin_amdgcn_sched_barrier(0); } while (0)
#define PH_END() do { __builtin_amdgcn_s_barrier(); \
    __builtin_amdgcn_sched_barrier(0); } while (0)

__device__ __forceinline__ bf16x8 ldsFrag(const __bf16* t, int row16, int kk, int fragOff) {
  // fragOff = ((l&15)<<5) + (((l>>4) ^ ((l>>1)&3))<<3), precomputed per thread
  int off = ((row16 >> 4) << 10) + (kk << 9) + fragOff;
  return *(const bf16x8*)&t[off];
}

template<int QM>
__device__ __forceinline__ void loadAF(const __bf16* tA, int wm, int fragOff, bf16x8 (&af)[4][2]) {
#pragma unroll
  for (int mi = 0; mi < 4; ++mi)
#pragma unroll
    for (int kk = 0; kk < 2; ++kk)
      af[mi][kk] = ldsFrag(tA, wm * 128 + (QM * 4 + mi) * 16, kk, fragOff);
}

template<int QN>
__device__ __forceinline__ void loadBF(const __bf16* tB, int wn, int fragOff, bf16x8 (&bfr)[2][2]) {
#pragma unroll
  for (int ni = 0; ni < 2; ++ni)
#pragma unroll
    for (int kk = 0; kk < 2; ++kk)
      bfr[ni][kk] = ldsFrag(tB, wn * 64 + (QN * 2 + ni) * 16, kk, fragOff);
}

template<int QM, int QN>
__device__ __forceinline__ void mfmaQuad(bf16x8 (&af)[4][2], bf16x8 (&bfr)[2][2], f32x4 (&acc)[8][4]) {
  __builtin_amdgcn_s_setprio(1);
#pragma unroll
  for (int mi = 0; mi < 4; ++mi)
#pragma unroll
    for (int ni = 0; ni < 2; ++ni)
#pragma unroll
      for (int kk = 0; kk < 2; ++kk)
        acc[QM * 4 + mi][QN * 2 + ni] = __builtin_amdgcn_mfma_f32_16x16x32_bf16(
            af[mi][kk], bfr[ni][kk], acc[QM * 4 + mi][QN * 2 + ni], 0, 0, 0);
  __builtin_amdgcn_s_setprio(0);
}

// Stage one 16-subtile unit: 2 global_load_lds per wave.
// UNIT 0: A bands {0-3,8-11}   (read as quadrant qm=0)
// UNIT 1: A bands {4-7,12-15}  (qm=1)
// UNIT 2: B bands {0,1,4,5,8,9,12,13}   (qn=0)
// UNIT 3: B bands {2,3,6,7,10,11,14,15} (qn=1)
template<int UNIT>
__device__ __forceinline__ void stageUnit(const __bf16* __restrict__ g, int gbase, int k0,
                                          __bf16* dst, int wid, int l) {
#pragma unroll
  for (int s = 0; s < 2; ++s) {
    int j = wid * 2 + s;
    int bi = j >> 1, cb = j & 1;
    int band;
    if constexpr (UNIT == 0)      band = bi + (bi & 4);
    else if constexpr (UNIT == 1) band = bi + (bi & 4) + 4;
    else if constexpr (UNIT == 2) band = ((bi >> 1) << 2) | (bi & 1);
    else                          band = (((bi >> 1) << 2) | (bi & 1)) + 2;
    const __bf16* src = g + (size_t)(gbase + band * 16 + (l >> 2)) * ND
                        + k0 + cb * 32 + (((l & 3) ^ ((l >> 3) & 3)) << 3);
    __builtin_amdgcn_global_load_lds(
        (const __attribute__((address_space(1))) void*)src,
        (__attribute__((address_space(3))) void*)(dst + ((band * 2 + cb) << 9)),
        16, 0, 0);
  }
}

__global__ __launch_bounds__(512, 2)
void gemm8_kernel(const __bf16* __restrict__ embB,
                  const int* __restrict__ key,
                  float* __restrict__ sum_exp,
                  float* __restrict__ numer) {
  __shared__ __bf16 sT[2][2][256 * 64];   // [buf][op A=0/B=1]  128 KiB
  __shared__ int keyR[256], keyC[256];

  // triangular decode over 32x32 tiles: t -> (bx >= by)
  const int t = blockIdx.x;
  int r = (int)((sqrtf(8.f * (float)t + 1.f) - 1.f) * 0.5f);
  while ((r + 1) * (r + 2) / 2 <= t) ++r;
  while (r * (r + 1) / 2 > t) --r;
  const int bx = r, by = t - r * (r + 1) / 2;
  const bool diag = (bx == by);
  const int rowBase = by * 256, colBase = bx * 256;

  const int tid = threadIdx.x;
  const int wid = tid >> 6;     // 0..7
  const int l   = tid & 63;
  const int wm  = wid >> 2;     // 0..1 (M)
  const int wn  = wid & 3;      // 0..3 (N)
  const int fragOff = ((l & 15) << 5) + ((((l >> 4)) ^ ((l >> 1) & 3)) << 3);

  if (tid < 256) keyR[tid] = key[rowBase + tid];
  else if (tid < 512) keyC[tid - 256] = key[colBase + tid - 256];
  __syncthreads();   // full drain: clean vmcnt/lgkmcnt ledger

  __bf16* tA0 = &sT[0][0][0]; __bf16* tB0 = &sT[0][1][0];
  __bf16* tA1 = &sT[1][0][0]; __bf16* tB1 = &sT[1][1][0];

  // prologue: K0 -> buf0 (all 4 units), K1 -> buf1 (units A0,B0)
  stageUnit<0>(embB, rowBase, 0, tA0, wid, l);
  stageUnit<1>(embB, rowBase, 0, tA0, wid, l);
  stageUnit<2>(embB, colBase, 0, tB0, wid, l);
  stageUnit<3>(embB, colBase, 0, tB0, wid, l);
  stageUnit<0>(embB, rowBase, 64, tA1, wid, l);
  stageUnit<2>(embB, colBase, 64, tB1, wid, l);
  asm volatile("s_waitcnt vmcnt(4)" ::: "memory");   // K0's 8 loads landed
  __builtin_amdgcn_s_barrier();
  __builtin_amdgcn_sched_barrier(0);

  f32x4 acc[8][4] = {};
  bf16x8 af[4][2], bfr[2][2];

  for (int i = 0; i < 8; ++i) {
    const int kA = (2 * i + 1) * 64;          // -> buf1 tail (units A1,B1)
    const int kB = (2 * i + 2) * 64;          // -> buf0 (all units)
    const int kC = (2 * i + 3) * 64;          // -> buf1 head (units A0,B0)
    const bool sB_ = (2 * i + 2) < 16;
    const bool sC  = (2 * i + 3) < 16;

    // p1: quad(0,0) of buf0
    loadAF<0>(tA0, wm, fragOff, af);
    loadBF<0>(tB0, wn, fragOff, bfr);
    stageUnit<1>(embB, rowBase, kA, tA1, wid, l);
    PH_SYNC(); mfmaQuad<0, 0>(af, bfr, acc); PH_END();
    // p2: quad(0,1) of buf0
    loadBF<1>(tB0, wn, fragOff, bfr);
    stageUnit<3>(embB, colBase, kA, tB1, wid, l);
    PH_SYNC(); mfmaQuad<0, 1>(af, bfr, acc); PH_END();
    // p3: quad(1,0) of buf0
    loadAF<1>(tA0, wm, fragOff, af);
    loadBF<0>(tB0, wn, fragOff, bfr);
    if (sB_) stageUnit<0>(embB, rowBase, kB, tA0, wid, l);
    PH_SYNC(); mfmaQuad<1, 0>(af, bfr, acc); PH_END();
    // p4: quad(1,1) of buf0; counted vmcnt -> buf1 (K 2i+1) fully landed
    loadBF<1>(tB0, wn, fragOff, bfr);
    if (sB_) stageUnit<2>(embB, colBase, kB, tB0, wid, l);
    PH_SYNC(); mfmaQuad<1, 1>(af, bfr, acc);
    if (sB_) { asm volatile("s_waitcnt vmcnt(4)" ::: "memory"); }
    else     { asm volatile("s_waitcnt vmcnt(0)" ::: "memory"); }
    PH_END();
    // p5: quad(0,0) of buf1
    loadAF<0>(tA1, wm, fragOff, af);
    loadBF<0>(tB1, wn, fragOff, bfr);
    if (sB_) stageUnit<1>(embB, rowBase, kB, tA0, wid, l);
    PH_SYNC(); mfmaQuad<0, 0>(af, bfr, acc); PH_END();
    // p6: quad(0,1) of buf1
    loadBF<1>(tB1, wn, fragOff, bfr);
    if (sB_) stageUnit<3>(embB, colBase, kB, tB0, wid, l);
    PH_SYNC(); mfmaQuad<0, 1>(af, bfr, acc); PH_END();
    // p7: quad(1,0) of buf1
    loadAF<1>(tA1, wm, fragOff, af);
    loadBF<0>(tB1, wn, fragOff, bfr);
    if (sC) stageUnit<0>(embB, rowBase, kC, tA1, wid, l);
    PH_SYNC(); mfmaQuad<1, 0>(af, bfr, acc); PH_END();
    // p8: quad(1,1) of buf1; counted vmcnt -> buf0 (K 2i+2) fully landed
    loadBF<1>(tB1, wn, fragOff, bfr);
    if (sC) stageUnit<2>(embB, colBase, kC, tB1, wid, l);
    PH_SYNC(); mfmaQuad<1, 1>(af, bfr, acc);
    if (sC) { asm volatile("s_waitcnt vmcnt(4)" ::: "memory"); }
    PH_END();
  }

  // ---------------- epilogue: exp + masked row/col sums --------------------
  float cse[4] = {0.f, 0.f, 0.f, 0.f};
  float cnu[4] = {0.f, 0.f, 0.f, 0.f};
#pragma unroll
  for (int m = 0; m < 8; ++m) {
#pragma unroll
    for (int r4 = 0; r4 < 4; ++r4) {
      int li = wm * 128 + m * 16 + (l >> 4) * 4 + r4;
      int gi = rowBase + li;
      int krow = keyR[li];
      float se = 0.f, nu = 0.f;
#pragma unroll
      for (int n = 0; n < 4; ++n) {
        int lj = wn * 64 + n * 16 + (l & 15);
        int gj = colBase + lj;
        float e = __expf(acc[m][n][r4] * SCALE);
        if (gi == gj) e = 0.f;
        bool match = (krow >= 0) && (krow == keyC[lj]);
        se += e;
        if (match) nu += e;
        if (!diag) {
          cse[n] += e;
          if (match) cnu[n] += e;
        }
      }
#pragma unroll
      for (int off = 8; off; off >>= 1) {
        se += __shfl_xor(se, off, 16);
        nu += __shfl_xor(nu, off, 16);
      }
      if ((l & 15) == 0) {
        atomicAdd(&sum_exp[gi], se);
        if (nu != 0.f) atomicAdd(&numer[gi], nu);
      }
    }
  }
  if (!diag) {
#pragma unroll
    for (int n = 0; n < 4; ++n) {
      cse[n] += __shfl_xor(cse[n], 16);
      cse[n] += __shfl_xor(cse[n], 32);
      cnu[n] += __shfl_xor(cnu[n], 16);
      cnu[n] += __shfl_xor(cnu[n], 32);
    }
    if (l < 16) {
#pragma unroll
      for (int n = 0; n < 4; ++n) {
        int gj = colBase + wn * 64 + n * 16 + l;
        atomicAdd(&sum_exp[gj], cse[n]);
        if (cnu[n] != 0.f) atomicAdd(&numer[gj], cnu[n]);
      }
    }
  }
}

// ---------------- fallback 128^2 fused kernel (small-ws path) --------------
__global__ __launch_bounds__(256, 4)
void gemm_fused_f32_kernel(const float* __restrict__ embF,
                           const int* __restrict__ key,
                           float* __restrict__ sum_exp,
                           float* __restrict__ numer) {
  __shared__ __bf16 sA[128 * 64];
  __shared__ __bf16 sB[128 * 64];
  __shared__ int keyR[128], keyC[128];

  const int t = blockIdx.x;
  int r = (int)((sqrtf(8.f * (float)t + 1.f) - 1.f) * 0.5f);
  while ((r + 1) * (r + 2) / 2 <= t) ++r;
  while (r * (r + 1) / 2 > t) --r;
  const int bx = r;
  const int by = t - r * (r + 1) / 2;
  const bool diag = (bx == by);

  const int tid = threadIdx.x;
  const int wid = tid >> 6;
  const int l   = tid & 63;
  const int wr  = wid >> 1;
  const int wc  = wid & 1;
  const int rowBase = by * 128;
  const int colBase = bx * 128;

  if (tid < 128) keyR[tid] = key[rowBase + tid];
  else           keyC[tid - 128] = key[colBase + tid - 128];

  f32x4 acc[4][4] = {};

  for (int k0 = 0; k0 < ND; k0 += 64) {
    __syncthreads();
#pragma unroll
    for (int c = 0; c < 4; ++c) {
      int chunk = tid + c * 256;
      int row = chunk >> 3;
      int ko  = (chunk & 7) * 8;
      const float* gfa = embF + (size_t)(rowBase + row) * ND + k0 + ko;
      const float* gfb = embF + (size_t)(colBase + row) * ND + k0 + ko;
      float4 a0 = *(const float4*)gfa;
      float4 a1 = *(const float4*)(gfa + 4);
      float4 b0 = *(const float4*)gfb;
      float4 b1 = *(const float4*)(gfb + 4);
      *(bf16x8*)&sA[row * 64 + ko] = cvt8(a0, a1);
      *(bf16x8*)&sB[row * 64 + ko] = cvt8(b0, b1);
    }
    __syncthreads();

#pragma unroll
    for (int kk = 0; kk < 2; ++kk) {
      bf16x8 af[4], bfr[4];
#pragma unroll
      for (int m = 0; m < 4; ++m)
        af[m] = *(const bf16x8*)&sA[(wr * 64 + m * 16 + (l & 15)) * 64 + kk * 32 + (l >> 4) * 8];
#pragma unroll
      for (int n = 0; n < 4; ++n)
        bfr[n] = *(const bf16x8*)&sB[(wc * 64 + n * 16 + (l & 15)) * 64 + kk * 32 + (l >> 4) * 8];
#pragma unroll
      for (int m = 0; m < 4; ++m)
#pragma unroll
        for (int n = 0; n < 4; ++n)
          acc[m][n] = __builtin_amdgcn_mfma_f32_16x16x32_bf16(af[m], bfr[n], acc[m][n], 0, 0, 0);
    }
  }

  float cse[4] = {0.f, 0.f, 0.f, 0.f};
  float cnu[4] = {0.f, 0.f, 0.f, 0.f};
#pragma unroll
  for (int m = 0; m < 4; ++m) {
#pragma unroll
    for (int r4 = 0; r4 < 4; ++r4) {
      int li = wr * 64 + m * 16 + (l >> 4) * 4 + r4;
      int gi = rowBase + li;
      int krow = keyR[li];
      float se = 0.f, nu = 0.f;
#pragma unroll
      for (int n = 0; n < 4; ++n) {
        int lj = wc * 64 + n * 16 + (l & 15);
        int gj = colBase + lj;
        float e = __expf(acc[m][n][r4] * SCALE);
        if (gi == gj) e = 0.f;
        bool match = (krow >= 0) && (krow == keyC[lj]);
        se += e;
        if (match) nu += e;
        if (!diag) {
          cse[n] += e;
          if (match) cnu[n] += e;
        }
      }
#pragma unroll
      for (int off = 8; off; off >>= 1) {
        se += __shfl_xor(se, off, 16);
        nu += __shfl_xor(nu, off, 16);
      }
      if ((l & 15) == 0) {
        atomicAdd(&sum_exp[gi], se);
        if (nu != 0.f) atomicAdd(&numer[gi], nu);
      }
    }
  }
  if (!diag) {
#pragma unroll
    for (int n = 0; n < 4; ++n) {
      cse[n] += __shfl_xor(cse[n], 16);
      cse[n] += __shfl_xor(cse[n], 32);
      cnu[n] += __shfl_xor(cnu[n], 16);
      cnu[n] += __shfl_xor(cnu[n], 32);
    }
    if (l < 16) {
#pragma unroll
      for (int n = 0; n < 4; ++n) {
        int gj = colBase + wc * 64 + n * 16 + l;
        atomicAdd(&sum_exp[gj], cse[n]);
        if (cnu[n] != 0.f) atomicAdd(&numer[gj], cnu[n]);
      }
    }
  }
}

// ---------------- finalize: histogram -> has_pos, losses, reductions -------
__global__ void finalize_kernel(const float* __restrict__ sum_exp,
                                const float* __restrict__ numer,
                                const int* __restrict__ key,
                                float* __restrict__ out) {
  __shared__ int cnt[128];
  __shared__ float wsum[16];
  __shared__ int wcnt[16];
  int tid = threadIdx.x;      // 1024 threads
  if (tid < 128) cnt[tid] = 0;
  __syncthreads();
  for (int i = tid; i < NB; i += 1024) {
    int k = key[i];
    if (k >= 0) atomicAdd(&cnt[k], 1);
  }
  __syncthreads();
  float ls = 0.f; int np = 0;
  for (int i = tid; i < NB; i += 1024) {
    int k = key[i];
    if (k >= 0 && cnt[k] >= 2) {
      np++;
      ls += logf(sum_exp[i] + 1e-8f) - logf(numer[i]);
    }
  }
  for (int off = 32; off; off >>= 1) {
    ls += __shfl_down(ls, off, 64);
    np += __shfl_down(np, off, 64);
  }
  int w = tid >> 6;
  if ((tid & 63) == 0) { wsum[w] = ls; wcnt[w] = np; }
  __syncthreads();
  if (tid == 0) {
    float s = 0.f; int n = 0;
    for (int i = 0; i < 16; ++i) { s += wsum[i]; n += wcnt[i]; }
    out[0] = (n > 0) ? (s / (float)n) : 0.f;
    out[1] = (float)n;
  }
}

// ---------------------------------------------------------------------------
#define NT32 32
#define NTRI32 (NT32 * (NT32 + 1) / 2)   // 528
#define NT128 64
#define NTRI128 (NT128 * (NT128 + 1) / 2) // 2080

extern "C" void kernel_launch(void* const* d_in, const int* in_sizes, int n_in,
                              void* d_out, int out_size, void* d_ws, size_t ws_size,
                              hipStream_t stream) {
  const float* emb = (const float*)d_in[0];
  const void* rel  = d_in[1];
  const void* ist  = d_in[2];
  float* out = (float*)d_out;

  const size_t embBytes = (size_t)NB * ND * sizeof(__bf16);   // 16 MiB
  const size_t smallBytes = (size_t)NB * 4 * 3;               // 96 KiB

  char* ws = (char*)d_ws;
  if (ws_size >= embBytes + smallBytes) {
    __bf16* embB   = (__bf16*)ws;
    float* sum_exp = (float*)(ws + embBytes);
    float* numer   = sum_exp + NB;
    int*   key     = (int*)(numer + NB);
    prep_kernel<<<4096, 256, 0, stream>>>(emb, rel, ist, embB, sum_exp, numer, key);
    gemm8_kernel<<<NTRI32, 512, 0, stream>>>(embB, key, sum_exp, numer);
    finalize_kernel<<<1, 1024, 0, stream>>>(sum_exp, numer, key, out);
  } else {
    float* sum_exp = (float*)ws;
    float* numer   = sum_exp + NB;
    int*   key     = (int*)(numer + NB);
    prep_small_kernel<<<32, 256, 0, stream>>>(rel, ist, sum_exp, numer, key);
    gemm_fused_f32_kernel<<<NTRI128, 256, 0, stream>>>(emb, key, sum_exp, numer);
    finalize_kernel<<<1, 1024, 0, stream>>>(sum_exp, numer, key, out);
  }
}

// Round 4
// 170.540 us; speedup vs baseline: 1.0150x; 1.0150x over previous
//
#include <hip/hip_runtime.h>
#include <hip/hip_bf16.h>
#include <stdint.h>

#define NB 8192
#define ND 1024
#define SCALE 20.0f   // 1/TEMPERATURE

typedef __bf16 bf16x8 __attribute__((ext_vector_type(8)));
typedef float  f32x4  __attribute__((ext_vector_type(4)));

// ---------------- input-format detection (device-side, deterministic) -------
__device__ inline void detect_formats(const void* rel_raw, const void* ist_raw,
                                      int& rel64, int& bmode) {
  const unsigned int* r = (const unsigned int*)rel_raw;
  int is64 = 1;
  for (int i = 1; i < 256; i += 2) {
    if (r[i] != 0u) { is64 = 0; break; }
  }
  rel64 = is64;
  const unsigned int* t = (const unsigned int*)ist_raw;
  bool sawf = false, sawbig = false;
  for (int i = 0; i < 64; ++i) {
    unsigned int w = t[i];
    if (w == 0x3F800000u) sawf = true;
    else if (w > 1u) sawbig = true;
  }
  bmode = sawf ? 2 : (sawbig ? 1 : 0);
}

__device__ inline int decode_key(const void* rel_raw, const void* ist_raw,
                                 int rel64, int bmode, int i) {
  const int* r32 = (const int*)rel_raw;
  int r = rel64 ? r32[2 * i] : r32[i];
  int truth;
  if (bmode == 1)      truth = (((const unsigned char*)ist_raw)[i] != 0);
  else if (bmode == 2) truth = (((const float*)ist_raw)[i] != 0.0f);
  else                 truth = (((const int*)ist_raw)[i] != 0);
  return truth ? r : -1;
}

__device__ inline bf16x8 cvt8(const float4& a, const float4& b) {
  bf16x8 v;
  v[0] = (__bf16)a.x; v[1] = (__bf16)a.y; v[2] = (__bf16)a.z; v[3] = (__bf16)a.w;
  v[4] = (__bf16)b.x; v[5] = (__bf16)b.y; v[6] = (__bf16)b.z; v[7] = (__bf16)b.w;
  return v;
}

// ---------------- prep: f32->bf16 convert + zero accumulators + decode keys -
__global__ void prep_kernel(const float* __restrict__ emb,
                            const void* __restrict__ rel_raw,
                            const void* __restrict__ ist_raw,
                            __bf16* __restrict__ embB,
                            float* __restrict__ sum_exp,
                            float* __restrict__ numer,
                            int* __restrict__ key) {
  int tid = blockIdx.x * 256 + threadIdx.x;
  size_t base = (size_t)tid * 8;
  if (base < (size_t)NB * ND) {
    float4 a = *(const float4*)(emb + base);
    float4 b = *(const float4*)(emb + base + 4);
    *(bf16x8*)(embB + base) = cvt8(a, b);
  }
  if (tid < NB) { sum_exp[tid] = 0.f; numer[tid] = 0.f; }
  __shared__ int s_rel64, s_bmode;
  if (blockIdx.x < 32) {                 // block-uniform branch
    if (threadIdx.x == 0) {
      int a, b; detect_formats(rel_raw, ist_raw, a, b);
      s_rel64 = a; s_bmode = b;
    }
    __syncthreads();
    int i = blockIdx.x * 256 + threadIdx.x;   // < 8192
    key[i] = decode_key(rel_raw, ist_raw, s_rel64, s_bmode, i);
  }
}

// small-ws fallback prep (no bf16 buffer)
__global__ void prep_small_kernel(const void* __restrict__ rel_raw,
                                  const void* __restrict__ ist_raw,
                                  float* __restrict__ sum_exp,
                                  float* __restrict__ numer,
                                  int* __restrict__ key) {
  int i = blockIdx.x * 256 + threadIdx.x;     // 32 blocks -> 8192
  sum_exp[i] = 0.f; numer[i] = 0.f;
  __shared__ int s_rel64, s_bmode;
  if (threadIdx.x == 0) {
    int a, b; detect_formats(rel_raw, ist_raw, a, b);
    s_rel64 = a; s_bmode = b;
  }
  __syncthreads();
  key[i] = decode_key(rel_raw, ist_raw, s_rel64, s_bmode, i);
}

// ============================================================================
// 8-phase 256x256 fused symmetric GEMM — template-faithful rewrite:
// NO sched_barrier (m141 lesson), counted vmcnt draining only old loads,
// XCD-swizzled grid.  LDS swizzle identical to round 3 (validated absmax=0).
// ============================================================================

__device__ __forceinline__ bf16x8 ldsFrag(const __bf16* t, int row16, int kk, int fragOff) {
  int off = ((row16 >> 4) << 10) + (kk << 9) + fragOff;
  return *(const bf16x8*)&t[off];
}

template<int QM>
__device__ __forceinline__ void loadAF(const __bf16* tA, int wm, int fragOff, bf16x8 (&af)[4][2]) {
#pragma unroll
  for (int mi = 0; mi < 4; ++mi)
#pragma unroll
    for (int kk = 0; kk < 2; ++kk)
      af[mi][kk] = ldsFrag(tA, wm * 128 + (QM * 4 + mi) * 16, kk, fragOff);
}

template<int QN>
__device__ __forceinline__ void loadBF(const __bf16* tB, int wn, int fragOff, bf16x8 (&bfr)[2][2]) {
#pragma unroll
  for (int ni = 0; ni < 2; ++ni)
#pragma unroll
    for (int kk = 0; kk < 2; ++kk)
      bfr[ni][kk] = ldsFrag(tB, wn * 64 + (QN * 2 + ni) * 16, kk, fragOff);
}

template<int QM, int QN>
__device__ __forceinline__ void mfmaQuad(bf16x8 (&af)[4][2], bf16x8 (&bfr)[2][2], f32x4 (&acc)[8][4]) {
  __builtin_amdgcn_s_setprio(1);
#pragma unroll
  for (int mi = 0; mi < 4; ++mi)
#pragma unroll
    for (int ni = 0; ni < 2; ++ni)
#pragma unroll
      for (int kk = 0; kk < 2; ++kk)
        acc[QM * 4 + mi][QN * 2 + ni] = __builtin_amdgcn_mfma_f32_16x16x32_bf16(
            af[mi][kk], bfr[ni][kk], acc[QM * 4 + mi][QN * 2 + ni], 0, 0, 0);
  __builtin_amdgcn_s_setprio(0);
}

// Stage one 16-subtile unit: 2 global_load_lds per wave.
// UNIT 0: A bands {0-3,8-11} (qm=0) | UNIT 1: A bands {4-7,12-15} (qm=1)
// UNIT 2: B bands {0,1,4,5,8,9,12,13} (qn=0) | UNIT 3: +2 (qn=1)
template<int UNIT>
__device__ __forceinline__ void stageUnit(const __bf16* __restrict__ g, int gbase, int k0,
                                          __bf16* dst, int wid, int l) {
#pragma unroll
  for (int s = 0; s < 2; ++s) {
    int j = wid * 2 + s;
    int bi = j >> 1, cb = j & 1;
    int band;
    if constexpr (UNIT == 0)      band = bi + (bi & 4);
    else if constexpr (UNIT == 1) band = bi + (bi & 4) + 4;
    else if constexpr (UNIT == 2) band = ((bi >> 1) << 2) | (bi & 1);
    else                          band = (((bi >> 1) << 2) | (bi & 1)) + 2;
    const __bf16* src = g + (size_t)(gbase + band * 16 + (l >> 2)) * ND
                        + k0 + cb * 32 + (((l & 3) ^ ((l >> 3) & 3)) << 3);
    __builtin_amdgcn_global_load_lds(
        (const __attribute__((address_space(1))) void*)src,
        (__attribute__((address_space(3))) void*)(dst + ((band * 2 + cb) << 9)),
        16, 0, 0);
  }
}

// One K-tile: 4 phases.  Stages A1/B1 of tile t+1 (other buf) at p1/p2,
// A0/B0 of tile t+2 (this buf, regions already consumed) at p3/p4.
// VM: 4 = steady-state counted wait; 0 = tail drain; -1 = none.
template<bool S1, bool S2, int VM>
__device__ __forceinline__ void kstep(const __bf16* bufA, const __bf16* bufB,
                                      __bf16* othA, __bf16* othB,
                                      const __bf16* __restrict__ embB,
                                      int rowBase, int colBase, int k1, int k2,
                                      int wid, int l, int wm, int wn, int fragOff,
                                      f32x4 (&acc)[8][4]) {
  bf16x8 af[4][2], bfr[2][2];
  // p1: quad(0,0)
  loadAF<0>(bufA, wm, fragOff, af);
  loadBF<0>(bufB, wn, fragOff, bfr);
  if constexpr (S1) stageUnit<1>(embB, rowBase, k1, othA, wid, l);
  __builtin_amdgcn_s_barrier();
  asm volatile("s_waitcnt lgkmcnt(0)" ::: "memory");
  mfmaQuad<0, 0>(af, bfr, acc);
  __builtin_amdgcn_s_barrier();
  // p2: quad(0,1)
  loadBF<1>(bufB, wn, fragOff, bfr);
  if constexpr (S1) stageUnit<3>(embB, colBase, k1, othB, wid, l);
  __builtin_amdgcn_s_barrier();
  asm volatile("s_waitcnt lgkmcnt(0)" ::: "memory");
  mfmaQuad<0, 1>(af, bfr, acc);
  __builtin_amdgcn_s_barrier();
  // p3: quad(1,0)  (A0 region of this buf free since p1 -> stage t+2 A0)
  loadAF<1>(bufA, wm, fragOff, af);
  loadBF<0>(bufB, wn, fragOff, bfr);
  if constexpr (S2) stageUnit<0>(embB, rowBase, k2, (__bf16*)bufA, wid, l);
  __builtin_amdgcn_s_barrier();
  asm volatile("s_waitcnt lgkmcnt(0)" ::: "memory");
  mfmaQuad<1, 0>(af, bfr, acc);
  __builtin_amdgcn_s_barrier();
  // p4: quad(1,1)  (B0 region free since p3 -> stage t+2 B0)
  loadBF<1>(bufB, wn, fragOff, bfr);
  if constexpr (S2) stageUnit<2>(embB, colBase, k2, (__bf16*)bufB, wid, l);
  __builtin_amdgcn_s_barrier();
  asm volatile("s_waitcnt lgkmcnt(0)" ::: "memory");
  mfmaQuad<1, 1>(af, bfr, acc);
  if constexpr (VM == 4)      asm volatile("s_waitcnt vmcnt(4)" ::: "memory");
  else if constexpr (VM == 0) asm volatile("s_waitcnt vmcnt(0)" ::: "memory");
  __builtin_amdgcn_s_barrier();
}

__global__ __launch_bounds__(512, 2)
void gemm8_kernel(const __bf16* __restrict__ embB,
                  const int* __restrict__ key,
                  float* __restrict__ sum_exp,
                  float* __restrict__ numer) {
  __shared__ __bf16 sT[2][2][256 * 64];   // [buf][op A=0/B=1]  128 KiB
  __shared__ int keyR[256], keyC[256];

  // XCD-chunked bijective swizzle (528 = 8 * 66), then triangular decode
  const int bid = blockIdx.x;
  const int t = (bid & 7) * 66 + (bid >> 3);
  int r = (int)((sqrtf(8.f * (float)t + 1.f) - 1.f) * 0.5f);
  while ((r + 1) * (r + 2) / 2 <= t) ++r;
  while (r * (r + 1) / 2 > t) --r;
  const int bx = r, by = t - r * (r + 1) / 2;
  const bool diag = (bx == by);
  const int rowBase = by * 256, colBase = bx * 256;

  const int tid = threadIdx.x;
  const int wid = tid >> 6;     // 0..7
  const int l   = tid & 63;
  const int wm  = wid >> 2;     // 0..1 (M)
  const int wn  = wid & 3;      // 0..3 (N)
  const int fragOff = ((l & 15) << 5) + ((((l >> 4)) ^ ((l >> 1) & 3)) << 3);

  // key loads first (their compiler-inserted vmcnt wait covers only these)
  if (tid < 256) keyR[tid] = key[rowBase + tid];
  else           keyC[tid - 256] = key[colBase + tid - 256];

  __bf16* tA0 = &sT[0][0][0]; __bf16* tB0 = &sT[0][1][0];
  __bf16* tA1 = &sT[1][0][0]; __bf16* tB1 = &sT[1][1][0];

  // prologue: tile0 full (4 units) -> buf0; tile1 A0,B0 -> buf1
  stageUnit<0>(embB, rowBase, 0, tA0, wid, l);
  stageUnit<1>(embB, rowBase, 0, tA0, wid, l);
  stageUnit<2>(embB, colBase, 0, tB0, wid, l);
  stageUnit<3>(embB, colBase, 0, tB0, wid, l);
  stageUnit<0>(embB, rowBase, 64, tA1, wid, l);
  stageUnit<2>(embB, colBase, 64, tB1, wid, l);
  asm volatile("s_waitcnt vmcnt(4)" ::: "memory");   // tile0's 8 loads landed
  __builtin_amdgcn_s_barrier();

  f32x4 acc[8][4] = {};

  // tiles 0..13: steady state (7 double-steps)
#pragma unroll 1
  for (int tt = 0; tt < 7; ++tt) {
    int k0 = tt * 128;
    kstep<true, true, 4>(tA0, tB0, tA1, tB1, embB, rowBase, colBase,
                         k0 + 64, k0 + 128, wid, l, wm, wn, fragOff, acc);
    kstep<true, true, 4>(tA1, tB1, tA0, tB0, embB, rowBase, colBase,
                         k0 + 128, k0 + 192, wid, l, wm, wn, fragOff, acc);
  }
  // tile 14: stage tile15 tail, drain all
  kstep<true, false, 0>(tA0, tB0, tA1, tB1, embB, rowBase, colBase,
                        15 * 64, 0, wid, l, wm, wn, fragOff, acc);
  // tile 15: no staging
  kstep<false, false, -1>(tA1, tB1, tA0, tB0, embB, rowBase, colBase,
                          0, 0, wid, l, wm, wn, fragOff, acc);

  // ---------------- epilogue: exp + masked row/col sums --------------------
  float cse[4] = {0.f, 0.f, 0.f, 0.f};
  float cnu[4] = {0.f, 0.f, 0.f, 0.f};
#pragma unroll
  for (int m = 0; m < 8; ++m) {
#pragma unroll
    for (int r4 = 0; r4 < 4; ++r4) {
      int li = wm * 128 + m * 16 + (l >> 4) * 4 + r4;
      int gi = rowBase + li;
      int krow = keyR[li];
      float se = 0.f, nu = 0.f;
#pragma unroll
      for (int n = 0; n < 4; ++n) {
        int lj = wn * 64 + n * 16 + (l & 15);
        int gj = colBase + lj;
        float e = __expf(acc[m][n][r4] * SCALE);
        if (gi == gj) e = 0.f;
        bool match = (krow >= 0) && (krow == keyC[lj]);
        se += e;
        if (match) nu += e;
        if (!diag) {
          cse[n] += e;
          if (match) cnu[n] += e;
        }
      }
#pragma unroll
      for (int off = 8; off; off >>= 1) {
        se += __shfl_xor(se, off, 16);
        nu += __shfl_xor(nu, off, 16);
      }
      if ((l & 15) == 0) {
        atomicAdd(&sum_exp[gi], se);
        if (nu != 0.f) atomicAdd(&numer[gi], nu);
      }
    }
  }
  if (!diag) {
#pragma unroll
    for (int n = 0; n < 4; ++n) {
      cse[n] += __shfl_xor(cse[n], 16);
      cse[n] += __shfl_xor(cse[n], 32);
      cnu[n] += __shfl_xor(cnu[n], 16);
      cnu[n] += __shfl_xor(cnu[n], 32);
    }
    if (l < 16) {
#pragma unroll
      for (int n = 0; n < 4; ++n) {
        int gj = colBase + wn * 64 + n * 16 + l;
        atomicAdd(&sum_exp[gj], cse[n]);
        if (cnu[n] != 0.f) atomicAdd(&numer[gj], cnu[n]);
      }
    }
  }
}

// ---------------- fallback 128^2 fused kernel (small-ws path) --------------
__global__ __launch_bounds__(256, 4)
void gemm_fused_f32_kernel(const float* __restrict__ embF,
                           const int* __restrict__ key,
                           float* __restrict__ sum_exp,
                           float* __restrict__ numer) {
  __shared__ __bf16 sA[128 * 64];
  __shared__ __bf16 sB[128 * 64];
  __shared__ int keyR[128], keyC[128];

  const int t = blockIdx.x;
  int r = (int)((sqrtf(8.f * (float)t + 1.f) - 1.f) * 0.5f);
  while ((r + 1) * (r + 2) / 2 <= t) ++r;
  while (r * (r + 1) / 2 > t) --r;
  const int bx = r;
  const int by = t - r * (r + 1) / 2;
  const bool diag = (bx == by);

  const int tid = threadIdx.x;
  const int wid = tid >> 6;
  const int l   = tid & 63;
  const int wr  = wid >> 1;
  const int wc  = wid & 1;
  const int rowBase = by * 128;
  const int colBase = bx * 128;

  if (tid < 128) keyR[tid] = key[rowBase + tid];
  else           keyC[tid - 128] = key[colBase + tid - 128];

  f32x4 acc[4][4] = {};

  for (int k0 = 0; k0 < ND; k0 += 64) {
    __syncthreads();
#pragma unroll
    for (int c = 0; c < 4; ++c) {
      int chunk = tid + c * 256;
      int row = chunk >> 3;
      int ko  = (chunk & 7) * 8;
      const float* gfa = embF + (size_t)(rowBase + row) * ND + k0 + ko;
      const float* gfb = embF + (size_t)(colBase + row) * ND + k0 + ko;
      float4 a0 = *(const float4*)gfa;
      float4 a1 = *(const float4*)(gfa + 4);
      float4 b0 = *(const float4*)gfb;
      float4 b1 = *(const float4*)(gfb + 4);
      *(bf16x8*)&sA[row * 64 + ko] = cvt8(a0, a1);
      *(bf16x8*)&sB[row * 64 + ko] = cvt8(b0, b1);
    }
    __syncthreads();

#pragma unroll
    for (int kk = 0; kk < 2; ++kk) {
      bf16x8 af[4], bfr[4];
#pragma unroll
      for (int m = 0; m < 4; ++m)
        af[m] = *(const bf16x8*)&sA[(wr * 64 + m * 16 + (l & 15)) * 64 + kk * 32 + (l >> 4) * 8];
#pragma unroll
      for (int n = 0; n < 4; ++n)
        bfr[n] = *(const bf16x8*)&sB[(wc * 64 + n * 16 + (l & 15)) * 64 + kk * 32 + (l >> 4) * 8];
#pragma unroll
      for (int m = 0; m < 4; ++m)
#pragma unroll
        for (int n = 0; n < 4; ++n)
          acc[m][n] = __builtin_amdgcn_mfma_f32_16x16x32_bf16(af[m], bfr[n], acc[m][n], 0, 0, 0);
    }
  }

  float cse[4] = {0.f, 0.f, 0.f, 0.f};
  float cnu[4] = {0.f, 0.f, 0.f, 0.f};
#pragma unroll
  for (int m = 0; m < 4; ++m) {
#pragma unroll
    for (int r4 = 0; r4 < 4; ++r4) {
      int li = wr * 64 + m * 16 + (l >> 4) * 4 + r4;
      int gi = rowBase + li;
      int krow = keyR[li];
      float se = 0.f, nu = 0.f;
#pragma unroll
      for (int n = 0; n < 4; ++n) {
        int lj = wc * 64 + n * 16 + (l & 15);
        int gj = colBase + lj;
        float e = __expf(acc[m][n][r4] * SCALE);
        if (gi == gj) e = 0.f;
        bool match = (krow >= 0) && (krow == keyC[lj]);
        se += e;
        if (match) nu += e;
        if (!diag) {
          cse[n] += e;
          if (match) cnu[n] += e;
        }
      }
#pragma unroll
      for (int off = 8; off; off >>= 1) {
        se += __shfl_xor(se, off, 16);
        nu += __shfl_xor(nu, off, 16);
      }
      if ((l & 15) == 0) {
        atomicAdd(&sum_exp[gi], se);
        if (nu != 0.f) atomicAdd(&numer[gi], nu);
      }
    }
  }
  if (!diag) {
#pragma unroll
    for (int n = 0; n < 4; ++n) {
      cse[n] += __shfl_xor(cse[n], 16);
      cse[n] += __shfl_xor(cse[n], 32);
      cnu[n] += __shfl_xor(cnu[n], 16);
      cnu[n] += __shfl_xor(cnu[n], 32);
    }
    if (l < 16) {
#pragma unroll
      for (int n = 0; n < 4; ++n) {
        int gj = colBase + wc * 64 + n * 16 + l;
        atomicAdd(&sum_exp[gj], cse[n]);
        if (cnu[n] != 0.f) atomicAdd(&numer[gj], cnu[n]);
      }
    }
  }
}

// ---------------- finalize: histogram -> has_pos, losses, reductions -------
__global__ void finalize_kernel(const float* __restrict__ sum_exp,
                                const float* __restrict__ numer,
                                const int* __restrict__ key,
                                float* __restrict__ out) {
  __shared__ int cnt[128];
  __shared__ float wsum[16];
  __shared__ int wcnt[16];
  int tid = threadIdx.x;      // 1024 threads
  if (tid < 128) cnt[tid] = 0;
  __syncthreads();
  for (int i = tid; i < NB; i += 1024) {
    int k = key[i];
    if (k >= 0) atomicAdd(&cnt[k], 1);
  }
  __syncthreads();
  float ls = 0.f; int np = 0;
  for (int i = tid; i < NB; i += 1024) {
    int k = key[i];
    if (k >= 0 && cnt[k] >= 2) {
      np++;
      ls += logf(sum_exp[i] + 1e-8f) - logf(numer[i]);
    }
  }
  for (int off = 32; off; off >>= 1) {
    ls += __shfl_down(ls, off, 64);
    np += __shfl_down(np, off, 64);
  }
  int w = tid >> 6;
  if ((tid & 63) == 0) { wsum[w] = ls; wcnt[w] = np; }
  __syncthreads();
  if (tid == 0) {
    float s = 0.f; int n = 0;
    for (int i = 0; i < 16; ++i) { s += wsum[i]; n += wcnt[i]; }
    out[0] = (n > 0) ? (s / (float)n) : 0.f;
    out[1] = (float)n;
  }
}

// ---------------------------------------------------------------------------
#define NT32 32
#define NTRI32 (NT32 * (NT32 + 1) / 2)   // 528
#define NT128 64
#define NTRI128 (NT128 * (NT128 + 1) / 2) // 2080

extern "C" void kernel_launch(void* const* d_in, const int* in_sizes, int n_in,
                              void* d_out, int out_size, void* d_ws, size_t ws_size,
                              hipStream_t stream) {
  const float* emb = (const float*)d_in[0];
  const void* rel  = d_in[1];
  const void* ist  = d_in[2];
  float* out = (float*)d_out;

  const size_t embBytes = (size_t)NB * ND * sizeof(__bf16);   // 16 MiB
  const size_t smallBytes = (size_t)NB * 4 * 3;               // 96 KiB

  char* ws = (char*)d_ws;
  if (ws_size >= embBytes + smallBytes) {
    __bf16* embB   = (__bf16*)ws;
    float* sum_exp = (float*)(ws + embBytes);
    float* numer   = sum_exp + NB;
    int*   key     = (int*)(numer + NB);
    prep_kernel<<<4096, 256, 0, stream>>>(emb, rel, ist, embB, sum_exp, numer, key);
    gemm8_kernel<<<NTRI32, 512, 0, stream>>>(embB, key, sum_exp, numer);
    finalize_kernel<<<1, 1024, 0, stream>>>(sum_exp, numer, key, out);
  } else {
    float* sum_exp = (float*)ws;
    float* numer   = sum_exp + NB;
    int*   key     = (int*)(numer + NB);
    prep_small_kernel<<<32, 256, 0, stream>>>(rel, ist, sum_exp, numer, key);
    gemm_fused_f32_kernel<<<NTRI128, 256, 0, stream>>>(emb, key, sum_exp, numer);
    finalize_kernel<<<1, 1024, 0, stream>>>(sum_exp, numer, key, out);
  }
}

// Round 5
// 135.838 us; speedup vs baseline: 1.2743x; 1.2555x over previous
//
#include <hip/hip_runtime.h>
#include <hip/hip_bf16.h>
#include <stdint.h>

#define NB 8192
#define ND 1024
#define SCALE 20.0f   // 1/TEMPERATURE

typedef __bf16 bf16x8 __attribute__((ext_vector_type(8)));
typedef float  f32x4  __attribute__((ext_vector_type(4)));

// ---------------- input-format detection (device-side, deterministic) -------
__device__ inline void detect_formats(const void* rel_raw, const void* ist_raw,
                                      int& rel64, int& bmode) {
  const unsigned int* r = (const unsigned int*)rel_raw;
  int is64 = 1;
  for (int i = 1; i < 256; i += 2) {
    if (r[i] != 0u) { is64 = 0; break; }
  }
  rel64 = is64;
  const unsigned int* t = (const unsigned int*)ist_raw;
  bool sawf = false, sawbig = false;
  for (int i = 0; i < 64; ++i) {
    unsigned int w = t[i];
    if (w == 0x3F800000u) sawf = true;
    else if (w > 1u) sawbig = true;
  }
  bmode = sawf ? 2 : (sawbig ? 1 : 0);
}

__device__ inline int decode_key(const void* rel_raw, const void* ist_raw,
                                 int rel64, int bmode, int i) {
  const int* r32 = (const int*)rel_raw;
  int r = rel64 ? r32[2 * i] : r32[i];
  int truth;
  if (bmode == 1)      truth = (((const unsigned char*)ist_raw)[i] != 0);
  else if (bmode == 2) truth = (((const float*)ist_raw)[i] != 0.0f);
  else                 truth = (((const int*)ist_raw)[i] != 0);
  return truth ? r : -1;
}

__device__ inline bf16x8 cvt8(const float4& a, const float4& b) {
  bf16x8 v;
  v[0] = (__bf16)a.x; v[1] = (__bf16)a.y; v[2] = (__bf16)a.z; v[3] = (__bf16)a.w;
  v[4] = (__bf16)b.x; v[5] = (__bf16)b.y; v[6] = (__bf16)b.z; v[7] = (__bf16)b.w;
  return v;
}

// ---------------- prep: f32->bf16 convert + zero accumulators + decode keys -
__global__ void prep_kernel(const float* __restrict__ emb,
                            const void* __restrict__ rel_raw,
                            const void* __restrict__ ist_raw,
                            __bf16* __restrict__ embB,
                            float* __restrict__ sum_exp,
                            float* __restrict__ numer,
                            int* __restrict__ key) {
  int tid = blockIdx.x * 256 + threadIdx.x;
  size_t base = (size_t)tid * 8;
  if (base < (size_t)NB * ND) {
    float4 a = *(const float4*)(emb + base);
    float4 b = *(const float4*)(emb + base + 4);
    *(bf16x8*)(embB + base) = cvt8(a, b);
  }
  if (tid < NB) { sum_exp[tid] = 0.f; numer[tid] = 0.f; }
  __shared__ int s_rel64, s_bmode;
  if (blockIdx.x < 32) {                 // block-uniform branch
    if (threadIdx.x == 0) {
      int a, b; detect_formats(rel_raw, ist_raw, a, b);
      s_rel64 = a; s_bmode = b;
    }
    __syncthreads();
    int i = blockIdx.x * 256 + threadIdx.x;   // < 8192
    key[i] = decode_key(rel_raw, ist_raw, s_rel64, s_bmode, i);
  }
}

// small-ws fallback prep (no bf16 buffer)
__global__ void prep_small_kernel(const void* __restrict__ rel_raw,
                                  const void* __restrict__ ist_raw,
                                  float* __restrict__ sum_exp,
                                  float* __restrict__ numer,
                                  int* __restrict__ key) {
  int i = blockIdx.x * 256 + threadIdx.x;     // 32 blocks -> 8192
  sum_exp[i] = 0.f; numer[i] = 0.f;
  __shared__ int s_rel64, s_bmode;
  if (threadIdx.x == 0) {
    int a, b; detect_formats(rel_raw, ist_raw, a, b);
    s_rel64 = a; s_bmode = b;
  }
  __syncthreads();
  key[i] = decode_key(rel_raw, ist_raw, s_rel64, s_bmode, i);
}

// ============================================================================
// Fused symmetric GEMM: 128x128 tile, 4 waves (2x2), BK=32 double-buffered,
// swizzled subtile LDS (conflict-free), ONE __syncthreads per K-tile.
// 33 KB LDS -> 4 blocks/CU co-resident (the m97/m114 overlap mechanism).
// LDS layout per operand per buffer: [band=row/16][16][32] subtiles (1 KB),
// 16B-block swizzle within a row: blk ^= (r4>>1)&3; staging source carries
// the same involution so global_load_lds stays linear (rule 21).
// ============================================================================

__global__ __launch_bounds__(256, 4)
void gemm_db_kernel(const __bf16* __restrict__ embB,
                    const int* __restrict__ key,
                    float* __restrict__ sum_exp,
                    float* __restrict__ numer) {
  __shared__ __bf16 sT[2][2][8 * 512];   // [buf][op A=0/B=1][band*512]  32 KB
  __shared__ int keyR[128], keyC[128];

  // XCD-chunked bijective swizzle (2080 = 8 * 260), then triangular decode
  const int bid = blockIdx.x;
  const int t = (bid & 7) * 260 + (bid >> 3);
  int r = (int)((sqrtf(8.f * (float)t + 1.f) - 1.f) * 0.5f);
  while ((r + 1) * (r + 2) / 2 <= t) ++r;
  while (r * (r + 1) / 2 > t) --r;
  const int bx = r, by = t - r * (r + 1) / 2;
  const bool diag = (bx == by);
  const int rowBase = by * 128, colBase = bx * 128;

  const int tid = threadIdx.x;
  const int wid = tid >> 6;     // 0..3
  const int l   = tid & 63;
  const int wr  = wid >> 1;     // wave row (0..1)
  const int wc  = wid & 1;      // wave col (0..1)
  // swizzled fragment offset within a [16][32] subtile (elements)
  const int fragOff = ((l & 15) << 5) + ((((l >> 4)) ^ ((l >> 1) & 3)) << 3);
  // staging source coords (inverse involution, LDS dest stays linear)
  const int srow = l >> 2;
  const int scol = ((l & 3) ^ ((l >> 3) & 3)) << 3;

  if (tid < 128) keyR[tid] = key[rowBase + tid];
  else           keyC[tid - 128] = key[colBase + tid - 128];

  // prologue: stage K-tile 0 into buf 0 (each wave: 2 A-bands + 2 B-bands)
#pragma unroll
  for (int s = 0; s < 2; ++s) {
    int band = wid * 2 + s;    // 0..7
    const __bf16* sa = embB + (size_t)(rowBase + band * 16 + srow) * ND + scol;
    const __bf16* sb = embB + (size_t)(colBase + band * 16 + srow) * ND + scol;
    __builtin_amdgcn_global_load_lds(
        (const __attribute__((address_space(1))) void*)sa,
        (__attribute__((address_space(3))) void*)&sT[0][0][band * 512], 16, 0, 0);
    __builtin_amdgcn_global_load_lds(
        (const __attribute__((address_space(1))) void*)sb,
        (__attribute__((address_space(3))) void*)&sT[0][1][band * 512], 16, 0, 0);
  }

  f32x4 acc[4][4] = {};

  for (int kt = 0; kt < 32; ++kt) {
    __syncthreads();   // drains vmcnt (staged tile kt landed) + prior LDS ops
    if (kt < 31) {     // stage K-tile kt+1 into the other buffer
      int k0 = (kt + 1) * 32;
      int nb = (kt + 1) & 1;
#pragma unroll
      for (int s = 0; s < 2; ++s) {
        int band = wid * 2 + s;
        const __bf16* sa = embB + (size_t)(rowBase + band * 16 + srow) * ND + k0 + scol;
        const __bf16* sb = embB + (size_t)(colBase + band * 16 + srow) * ND + k0 + scol;
        __builtin_amdgcn_global_load_lds(
            (const __attribute__((address_space(1))) void*)sa,
            (__attribute__((address_space(3))) void*)&sT[nb][0][band * 512], 16, 0, 0);
        __builtin_amdgcn_global_load_lds(
            (const __attribute__((address_space(1))) void*)sb,
            (__attribute__((address_space(3))) void*)&sT[nb][1][band * 512], 16, 0, 0);
      }
    }
    const __bf16* cA = &sT[kt & 1][0][0];
    const __bf16* cB = &sT[kt & 1][1][0];
    bf16x8 af[4], bfr[4];
#pragma unroll
    for (int m = 0; m < 4; ++m)
      af[m] = *(const bf16x8*)&cA[(wr * 4 + m) * 512 + fragOff];
#pragma unroll
    for (int n = 0; n < 4; ++n)
      bfr[n] = *(const bf16x8*)&cB[(wc * 4 + n) * 512 + fragOff];
#pragma unroll
    for (int m = 0; m < 4; ++m)
#pragma unroll
      for (int n = 0; n < 4; ++n)
        acc[m][n] = __builtin_amdgcn_mfma_f32_16x16x32_bf16(af[m], bfr[n], acc[m][n], 0, 0, 0);
  }

  // epilogue: C/D layout col = lane&15, row = (lane>>4)*4 + reg
  float cse[4] = {0.f, 0.f, 0.f, 0.f};   // per-col partials (off-diag only)
  float cnu[4] = {0.f, 0.f, 0.f, 0.f};
#pragma unroll
  for (int m = 0; m < 4; ++m) {
#pragma unroll
    for (int r4 = 0; r4 < 4; ++r4) {
      int li = wr * 64 + m * 16 + (l >> 4) * 4 + r4;
      int gi = rowBase + li;
      int krow = keyR[li];
      float se = 0.f, nu = 0.f;
#pragma unroll
      for (int n = 0; n < 4; ++n) {
        int lj = wc * 64 + n * 16 + (l & 15);
        int gj = colBase + lj;
        float e = __expf(acc[m][n][r4] * SCALE);
        if (gi == gj) e = 0.f;          // only possible on diagonal tiles
        bool match = (krow >= 0) && (krow == keyC[lj]);
        se += e;
        if (match) nu += e;
        if (!diag) {
          cse[n] += e;
          if (match) cnu[n] += e;
        }
      }
#pragma unroll
      for (int off = 8; off; off >>= 1) {
        se += __shfl_xor(se, off, 16);
        nu += __shfl_xor(nu, off, 16);
      }
      if ((l & 15) == 0) {
        atomicAdd(&sum_exp[gi], se);
        if (nu != 0.f) atomicAdd(&numer[gi], nu);
      }
    }
  }
  if (!diag) {
#pragma unroll
    for (int n = 0; n < 4; ++n) {
      cse[n] += __shfl_xor(cse[n], 16);
      cse[n] += __shfl_xor(cse[n], 32);
      cnu[n] += __shfl_xor(cnu[n], 16);
      cnu[n] += __shfl_xor(cnu[n], 32);
    }
    if (l < 16) {
#pragma unroll
      for (int n = 0; n < 4; ++n) {
        int gj = colBase + wc * 64 + n * 16 + l;
        atomicAdd(&sum_exp[gj], cse[n]);
        if (cnu[n] != 0.f) atomicAdd(&numer[gj], cnu[n]);
      }
    }
  }
}

// ---------------- fallback 128^2 fused kernel (small-ws path) --------------
__global__ __launch_bounds__(256, 4)
void gemm_fused_f32_kernel(const float* __restrict__ embF,
                           const int* __restrict__ key,
                           float* __restrict__ sum_exp,
                           float* __restrict__ numer) {
  __shared__ __bf16 sA[128 * 64];
  __shared__ __bf16 sB[128 * 64];
  __shared__ int keyR[128], keyC[128];

  const int t = blockIdx.x;
  int r = (int)((sqrtf(8.f * (float)t + 1.f) - 1.f) * 0.5f);
  while ((r + 1) * (r + 2) / 2 <= t) ++r;
  while (r * (r + 1) / 2 > t) --r;
  const int bx = r;
  const int by = t - r * (r + 1) / 2;
  const bool diag = (bx == by);

  const int tid = threadIdx.x;
  const int wid = tid >> 6;
  const int l   = tid & 63;
  const int wr  = wid >> 1;
  const int wc  = wid & 1;
  const int rowBase = by * 128;
  const int colBase = bx * 128;

  if (tid < 128) keyR[tid] = key[rowBase + tid];
  else           keyC[tid - 128] = key[colBase + tid - 128];

  f32x4 acc[4][4] = {};

  for (int k0 = 0; k0 < ND; k0 += 64) {
    __syncthreads();
#pragma unroll
    for (int c = 0; c < 4; ++c) {
      int chunk = tid + c * 256;
      int row = chunk >> 3;
      int ko  = (chunk & 7) * 8;
      const float* gfa = embF + (size_t)(rowBase + row) * ND + k0 + ko;
      const float* gfb = embF + (size_t)(colBase + row) * ND + k0 + ko;
      float4 a0 = *(const float4*)gfa;
      float4 a1 = *(const float4*)(gfa + 4);
      float4 b0 = *(const float4*)gfb;
      float4 b1 = *(const float4*)(gfb + 4);
      *(bf16x8*)&sA[row * 64 + ko] = cvt8(a0, a1);
      *(bf16x8*)&sB[row * 64 + ko] = cvt8(b0, b1);
    }
    __syncthreads();

#pragma unroll
    for (int kk = 0; kk < 2; ++kk) {
      bf16x8 af[4], bfr[4];
#pragma unroll
      for (int m = 0; m < 4; ++m)
        af[m] = *(const bf16x8*)&sA[(wr * 64 + m * 16 + (l & 15)) * 64 + kk * 32 + (l >> 4) * 8];
#pragma unroll
      for (int n = 0; n < 4; ++n)
        bfr[n] = *(const bf16x8*)&sB[(wc * 64 + n * 16 + (l & 15)) * 64 + kk * 32 + (l >> 4) * 8];
#pragma unroll
      for (int m = 0; m < 4; ++m)
#pragma unroll
        for (int n = 0; n < 4; ++n)
          acc[m][n] = __builtin_amdgcn_mfma_f32_16x16x32_bf16(af[m], bfr[n], acc[m][n], 0, 0, 0);
    }
  }

  float cse[4] = {0.f, 0.f, 0.f, 0.f};
  float cnu[4] = {0.f, 0.f, 0.f, 0.f};
#pragma unroll
  for (int m = 0; m < 4; ++m) {
#pragma unroll
    for (int r4 = 0; r4 < 4; ++r4) {
      int li = wr * 64 + m * 16 + (l >> 4) * 4 + r4;
      int gi = rowBase + li;
      int krow = keyR[li];
      float se = 0.f, nu = 0.f;
#pragma unroll
      for (int n = 0; n < 4; ++n) {
        int lj = wc * 64 + n * 16 + (l & 15);
        int gj = colBase + lj;
        float e = __expf(acc[m][n][r4] * SCALE);
        if (gi == gj) e = 0.f;
        bool match = (krow >= 0) && (krow == keyC[lj]);
        se += e;
        if (match) nu += e;
        if (!diag) {
          cse[n] += e;
          if (match) cnu[n] += e;
        }
      }
#pragma unroll
      for (int off = 8; off; off >>= 1) {
        se += __shfl_xor(se, off, 16);
        nu += __shfl_xor(nu, off, 16);
      }
      if ((l & 15) == 0) {
        atomicAdd(&sum_exp[gi], se);
        if (nu != 0.f) atomicAdd(&numer[gi], nu);
      }
    }
  }
  if (!diag) {
#pragma unroll
    for (int n = 0; n < 4; ++n) {
      cse[n] += __shfl_xor(cse[n], 16);
      cse[n] += __shfl_xor(cse[n], 32);
      cnu[n] += __shfl_xor(cnu[n], 16);
      cnu[n] += __shfl_xor(cnu[n], 32);
    }
    if (l < 16) {
#pragma unroll
      for (int n = 0; n < 4; ++n) {
        int gj = colBase + wc * 64 + n * 16 + l;
        atomicAdd(&sum_exp[gj], cse[n]);
        if (cnu[n] != 0.f) atomicAdd(&numer[gj], cnu[n]);
      }
    }
  }
}

// ---------------- finalize: histogram -> has_pos, losses, reductions -------
__global__ void finalize_kernel(const float* __restrict__ sum_exp,
                                const float* __restrict__ numer,
                                const int* __restrict__ key,
                                float* __restrict__ out) {
  __shared__ int cnt[128];
  __shared__ float wsum[16];
  __shared__ int wcnt[16];
  int tid = threadIdx.x;      // 1024 threads
  if (tid < 128) cnt[tid] = 0;
  __syncthreads();
  for (int i = tid; i < NB; i += 1024) {
    int k = key[i];
    if (k >= 0) atomicAdd(&cnt[k], 1);
  }
  __syncthreads();
  float ls = 0.f; int np = 0;
  for (int i = tid; i < NB; i += 1024) {
    int k = key[i];
    if (k >= 0 && cnt[k] >= 2) {
      np++;
      ls += logf(sum_exp[i] + 1e-8f) - logf(numer[i]);
    }
  }
  for (int off = 32; off; off >>= 1) {
    ls += __shfl_down(ls, off, 64);
    np += __shfl_down(np, off, 64);
  }
  int w = tid >> 6;
  if ((tid & 63) == 0) { wsum[w] = ls; wcnt[w] = np; }
  __syncthreads();
  if (tid == 0) {
    float s = 0.f; int n = 0;
    for (int i = 0; i < 16; ++i) { s += wsum[i]; n += wcnt[i]; }
    out[0] = (n > 0) ? (s / (float)n) : 0.f;
    out[1] = (float)n;
  }
}

// ---------------------------------------------------------------------------
#define NT128 64
#define NTRI128 (NT128 * (NT128 + 1) / 2) // 2080

extern "C" void kernel_launch(void* const* d_in, const int* in_sizes, int n_in,
                              void* d_out, int out_size, void* d_ws, size_t ws_size,
                              hipStream_t stream) {
  const float* emb = (const float*)d_in[0];
  const void* rel  = d_in[1];
  const void* ist  = d_in[2];
  float* out = (float*)d_out;

  const size_t embBytes = (size_t)NB * ND * sizeof(__bf16);   // 16 MiB
  const size_t smallBytes = (size_t)NB * 4 * 3;               // 96 KiB

  char* ws = (char*)d_ws;
  if (ws_size >= embBytes + smallBytes) {
    __bf16* embB   = (__bf16*)ws;
    float* sum_exp = (float*)(ws + embBytes);
    float* numer   = sum_exp + NB;
    int*   key     = (int*)(numer + NB);
    prep_kernel<<<4096, 256, 0, stream>>>(emb, rel, ist, embB, sum_exp, numer, key);
    gemm_db_kernel<<<NTRI128, 256, 0, stream>>>(embB, key, sum_exp, numer);
    finalize_kernel<<<1, 1024, 0, stream>>>(sum_exp, numer, key, out);
  } else {
    float* sum_exp = (float*)ws;
    float* numer   = sum_exp + NB;
    int*   key     = (int*)(numer + NB);
    prep_small_kernel<<<32, 256, 0, stream>>>(rel, ist, sum_exp, numer, key);
    gemm_fused_f32_kernel<<<NTRI128, 256, 0, stream>>>(emb, key, sum_exp, numer);
    finalize_kernel<<<1, 1024, 0, stream>>>(sum_exp, numer, key, out);
  }
}